// Round 5
// baseline (702.172 us; speedup 1.0000x reference)
//
#include <hip/hip_runtime.h>
#include <hip/hip_bf16.h>
#include <cmath>

#define CDIV(a, b) (((a) + (b) - 1) / (b))

typedef __attribute__((ext_vector_type(8))) short bf16x8;
typedef __attribute__((ext_vector_type(4))) short s16x4;
typedef __attribute__((ext_vector_type(4))) float f32x4;

__device__ __forceinline__ short f2bf(float f) {
    unsigned u = __float_as_uint(f);
    unsigned r = (u + 0x7fff + ((u >> 16) & 1)) >> 16;
    return (short)r;
}
__device__ __forceinline__ float bf2f(short s) {
    return __uint_as_float(((unsigned)(unsigned short)s) << 16);
}

__device__ __forceinline__ void gll16(const void* g, void* l) {
    __builtin_amdgcn_global_load_lds((const __attribute__((address_space(1))) void*)g,
                                     (__attribute__((address_space(3))) void*)l, 16, 0, 0);
}

// ---------------------------------------------------------------------------
// C-blocked fusion: 4 channels x 4 pixels per thread. TIN: 0 fp32, 1 bf16 NCHW.
// Writes fp32 NCHW out only.
// ---------------------------------------------------------------------------
template <int TIN>
__global__ void fusionC_kernel(const void* __restrict__ featv,
                               const float* __restrict__ kv,
                               const float* __restrict__ kh,
                               const float* __restrict__ m,
                               float* __restrict__ out,
                               int B, int C, int H, int W, int total) {
    int idx = blockIdx.x * blockDim.x + threadIdx.x;
    if (idx >= total) return;
    int Wg = W >> 2;
    int C4 = C >> 2;
    int g = idx % Wg;
    int cg = (idx / Wg) % C4;
    int y = (idx / (Wg * C4)) % H;
    int b = idx / (Wg * C4 * H);
    int x0 = g << 2, c0 = cg << 2;
    int HW = H * W;

    int yy[5];
#pragma unroll
    for (int i = 0; i < 5; ++i) {
        int t = y + i - 2;
        yy[i] = t < 0 ? 0 : (t >= H ? H - 1 : t);
    }
    const float* kvb = kv + ((size_t)b * 5 * H + y) * W + x0;
    const float* khb = kh + ((size_t)b * 5 * H + y) * W + x0;
    f32x4 kvv[5], khv[5];
#pragma unroll
    for (int i = 0; i < 5; ++i) {
        kvv[i] = *(const f32x4*)(kvb + (size_t)i * HW);
        khv[i] = *(const f32x4*)(khb + (size_t)i * HW);
    }
    f32x4 m4 = *(const f32x4*)(m + ((size_t)b * H + y) * W + x0);
    bool interior = (g >= 1 && g <= Wg - 2);

#pragma unroll
    for (int cc = 0; cc < 4; ++cc) {
        size_t plane = (size_t)(b * C + c0 + cc) * HW;
        const float* fpf = (const float*)featv + plane;
        const short* fpb = (const short*)featv + plane;
        f32x4 acc = (f32x4){0.f, 0.f, 0.f, 0.f};
        f32x4 ctr;
        if (interior) {
#pragma unroll
            for (int i = 0; i < 5; ++i) {
                float w8[8];
                if (TIN == 0) {
                    const float* row = fpf + (size_t)yy[i] * W + x0;
                    f32x4 Lv = *(const f32x4*)(row - 4);
                    f32x4 Cv = *(const f32x4*)(row);
                    f32x4 Rv = *(const f32x4*)(row + 4);
                    w8[0] = Lv[2]; w8[1] = Lv[3];
                    w8[2] = Cv[0]; w8[3] = Cv[1]; w8[4] = Cv[2]; w8[5] = Cv[3];
                    w8[6] = Rv[0]; w8[7] = Rv[1];
                    if (i == 2) ctr = Cv;
                } else {
                    const short* row = fpb + (size_t)yy[i] * W + x0;
                    s16x4 Lv = *(const s16x4*)(row - 4);
                    s16x4 Cv = *(const s16x4*)(row);
                    s16x4 Rv = *(const s16x4*)(row + 4);
                    w8[0] = bf2f(Lv[2]); w8[1] = bf2f(Lv[3]);
                    w8[2] = bf2f(Cv[0]); w8[3] = bf2f(Cv[1]);
                    w8[4] = bf2f(Cv[2]); w8[5] = bf2f(Cv[3]);
                    w8[6] = bf2f(Rv[0]); w8[7] = bf2f(Rv[1]);
                    if (i == 2) {
                        ctr[0] = w8[2]; ctr[1] = w8[3]; ctr[2] = w8[4]; ctr[3] = w8[5];
                    }
                }
#pragma unroll
                for (int o = 0; o < 4; ++o) {
                    float r = 0.f;
#pragma unroll
                    for (int j = 0; j < 5; ++j) r = fmaf(khv[j][o], w8[o + j], r);
                    acc[o] = fmaf(kvv[i][o], r, acc[o]);
                }
            }
        } else {
#pragma unroll
            for (int o = 0; o < 4; ++o) {
                int x = x0 + o;
                int xx[5];
#pragma unroll
                for (int j = 0; j < 5; ++j) {
                    int u = x + j - 2;
                    xx[j] = u < 0 ? 0 : (u >= W ? W - 1 : u);
                }
                float a = 0.f;
#pragma unroll
                for (int i = 0; i < 5; ++i) {
                    float r = 0.f;
#pragma unroll
                    for (int j = 0; j < 5; ++j) {
                        float fv = (TIN == 0) ? fpf[(size_t)yy[i] * W + xx[j]]
                                              : bf2f(fpb[(size_t)yy[i] * W + xx[j]]);
                        r = fmaf(khv[j][o], fv, r);
                    }
                    a = fmaf(kvv[i][o], r, a);
                }
                acc[o] = a;
                ctr[o] = (TIN == 0) ? fpf[(size_t)y * W + x] : bf2f(fpb[(size_t)y * W + x]);
            }
        }
        f32x4 o4;
#pragma unroll
        for (int o = 0; o < 4; ++o) o4[o] = m4[o] * acc[o] + (1.f - m4[o]) * ctr[o];
        *(f32x4*)(out + plane + (size_t)y * W + x0) = o4;
    }
}

// scalar-C fusion for C=3 final output, bf16 input
__global__ void fusion4b_kernel(const short* __restrict__ feat,
                                const float* __restrict__ kv,
                                const float* __restrict__ kh,
                                const float* __restrict__ m,
                                float* __restrict__ out,
                                int B, int C, int H, int W, int total) {
    int idx = blockIdx.x * blockDim.x + threadIdx.x;
    if (idx >= total) return;
    int Wg = W >> 2;
    int g = idx % Wg;
    int y = (idx / Wg) % H;
    int c = (idx / (Wg * H)) % C;
    int b = idx / (Wg * H * C);
    int x0 = g << 2;
    int HW = H * W;

    const short* fp = feat + (size_t)(b * C + c) * HW;
    int yy[5];
#pragma unroll
    for (int i = 0; i < 5; ++i) {
        int t = y + i - 2;
        yy[i] = t < 0 ? 0 : (t >= H ? H - 1 : t);
    }
    const float* kvb = kv + ((size_t)b * 5 * H + y) * W + x0;
    const float* khb = kh + ((size_t)b * 5 * H + y) * W + x0;

    f32x4 res, c4;
    if (g >= 1 && g <= Wg - 2) {
        f32x4 kvv[5], khv[5];
#pragma unroll
        for (int i = 0; i < 5; ++i) {
            kvv[i] = *(const f32x4*)(kvb + (size_t)i * HW);
            khv[i] = *(const f32x4*)(khb + (size_t)i * HW);
        }
        f32x4 acc = (f32x4){0.f, 0.f, 0.f, 0.f};
#pragma unroll
        for (int i = 0; i < 5; ++i) {
            const short* row = fp + (size_t)yy[i] * W + x0;
            s16x4 Lv = *(const s16x4*)(row - 4);
            s16x4 Cv = *(const s16x4*)(row);
            s16x4 Rv = *(const s16x4*)(row + 4);
            float w8[8] = {bf2f(Lv[2]), bf2f(Lv[3]), bf2f(Cv[0]), bf2f(Cv[1]),
                           bf2f(Cv[2]), bf2f(Cv[3]), bf2f(Rv[0]), bf2f(Rv[1])};
            if (i == 2) { c4[0] = w8[2]; c4[1] = w8[3]; c4[2] = w8[4]; c4[3] = w8[5]; }
#pragma unroll
            for (int o = 0; o < 4; ++o) {
                float r = 0.f;
#pragma unroll
                for (int j = 0; j < 5; ++j) r = fmaf(khv[j][o], w8[o + j], r);
                acc[o] = fmaf(kvv[i][o], r, acc[o]);
            }
        }
        res = acc;
    } else {
#pragma unroll
        for (int o = 0; o < 4; ++o) {
            int x = x0 + o;
            int xx[5];
#pragma unroll
            for (int j = 0; j < 5; ++j) {
                int u = x + j - 2;
                xx[j] = u < 0 ? 0 : (u >= W ? W - 1 : u);
            }
            float acc = 0.f;
#pragma unroll
            for (int i = 0; i < 5; ++i) {
                float r = 0.f;
#pragma unroll
                for (int j = 0; j < 5; ++j)
                    r = fmaf(khb[(size_t)j * HW + o], bf2f(fp[(size_t)yy[i] * W + xx[j]]), r);
                acc = fmaf(kvb[(size_t)i * HW + o], r, acc);
            }
            res[o] = acc;
            c4[o] = bf2f(fp[(size_t)y * W + x]);
        }
    }
    f32x4 m4 = *(const f32x4*)(m + ((size_t)b * H + y) * W + x0);
    f32x4 o4;
#pragma unroll
    for (int o = 0; o < 4; ++o) o4[o] = m4[o] * res[o] + (1.f - m4[o]) * c4[o];
    *(f32x4*)(out + ((size_t)(b * C + c) * H + y) * W + x0) = o4;
}

// ---------------------------------------------------------------------------
// Pad: fp32 NCHW -> bf16 NHWC pin, zeroing borders. y = yp - po.
// ---------------------------------------------------------------------------
__global__ void pad_kernel(const float* __restrict__ in, short* __restrict__ pin,
                           int C, int H, int W, int Hp, int Wp, int po, int total) {
    int tid = blockIdx.x * blockDim.x + threadIdx.x;
    if (tid >= total) return;
    int C8 = C >> 3;
    int c8 = tid % C8;
    int xp = (tid / C8) % Wp;
    int yp = (tid / (C8 * Wp)) % Hp;
    int b = tid / (C8 * Wp * Hp);

    int y = yp - po, x = xp - po;
    bool valid = (y >= 0 && y < H && x >= 0 && x < W);
    bf16x8 v;
    if (valid) {
        const float* ip = in + ((size_t)(b * C + c8 * 8) * H + y) * W + x;
        size_t HW = (size_t)H * W;
#pragma unroll
        for (int k = 0; k < 8; ++k) v[k] = f2bf(ip[k * HW]);
    } else {
        v = (bf16x8)0;
    }
    *(bf16x8*)(pin + (size_t)tid * 8) = v;
}

// zero pad borders of NHWC bf16 pin. mode1: all 4 edges; mode0: high edges only.
__global__ void zb_kernel(short* __restrict__ buf, int Hp, int Wp, int C8, int mode,
                          int total) {
    int tid = blockIdx.x * blockDim.x + threadIdx.x;
    if (tid >= total) return;
    int xp = (tid / C8) % Wp;
    int yp = (tid / (C8 * Wp)) % Hp;
    bool border = mode ? (yp == 0 || yp == Hp - 1 || xp == 0 || xp == Wp - 1)
                       : (yp == Hp - 1 || xp == Wp - 1);
    if (border) *(bf16x8*)(buf + (size_t)tid * 8) = (bf16x8)0;
}

// ---------------------------------------------------------------------------
// Weight transform (verified): wt[t9][m][ci]; s2 packs phase blocks
// {1,2,2,4} at offsets {0,1,3,5}.
// ---------------------------------------------------------------------------
__global__ void wtrans_kernel(const float* __restrict__ w, short* __restrict__ wt,
                              int Cin, int Cout, int Mp, int stride, int total) {
    int tid = blockIdx.x * blockDim.x + threadIdx.x;
    if (tid >= total) return;
    int ci = tid % Cin;
    int mm = (tid / Cin) % Mp;
    int t9 = tid / (Cin * Mp);
    int i, j;
    if (stride == 1) {
        int a = t9 / 3, bb = t9 % 3;
        i = 2 - a; j = 2 - bb;
    } else {
        int py, px, a, bb;
        if (t9 == 0) { py = 0; px = 0; a = 0; bb = 0; }
        else if (t9 < 3) { py = 0; px = 1; a = 0; bb = t9 - 1; }
        else if (t9 < 5) { py = 1; px = 0; a = t9 - 3; bb = 0; }
        else { int tt = t9 - 5; py = 1; px = 1; a = tt >> 1; bb = tt & 1; }
        i = (py == 0) ? 1 : (a == 0 ? 2 : 0);
        j = (px == 0) ? 1 : (bb == 0 ? 2 : 0);
    }
    float v = 0.f;
    if (mm < Cout) v = w[((ci * Cout + mm) * 3 + i) * 3 + j];
    wt[tid] = f2bf(v);
}

// ---------------------------------------------------------------------------
// Implicit-GEMM convT, BM x BN tile, 4 waves, BK=64, XOR-swizzled LDS.
// S2: blockIdx.z = phase. OUTM 1: bf16 NHWC pin. OUTM 2: bf16 NCHW (+act).
// ---------------------------------------------------------------------------
template <int BM, int BN, bool S2, int OUTM, int ACT>
__global__ void convt_mfma(const short* __restrict__ pin, const short* __restrict__ wtc,
                           float* __restrict__ outf, short* __restrict__ outb,
                           int Hpin, int Wpin, int Cin, int Mp, int Cout,
                           int Ho, int Wo, int Hu, int Wv,
                           int Hop, int Wop, int poff) {
    constexpr int WAVES_M = (BM >= 128) ? 2 : 1;
    constexpr int WM = BM / WAVES_M;
    constexpr int WN = BN / (4 / WAVES_M);
    constexpr int FM = WM / 16, FN = WN / 16;
    constexpr int RB = BN / 32;
    __shared__ __align__(16) short Alds[BM * 64];
    __shared__ __align__(16) short Blds[BN * 64];

    int t = threadIdx.x, lane = t & 63, wid = t >> 6;
    int n0 = blockIdx.x * BN, m0 = blockIdx.y * BM;

    int py = 0, px = 0, ny = 3, nx = 3, dys = 0x210, dxs = 0x210, sy = 1;
    const short* wt = wtc;
    if (S2) {
        int pz = blockIdx.z;
        py = pz >> 1; px = pz & 1;
        ny = 1 + py; nx = 1 + px;
        dys = py ? 0x10 : 0; dxs = px ? 0x10 : 0;
        int pre = (pz == 0) ? 0 : (pz == 1) ? 1 : (pz == 2) ? 3 : 5;
        wt = wtc + (size_t)pre * Mp * Cin;
        sy = 2;
    }

    int rowS = t >> 3;
    int dS = (t & 7) ^ (rowS & 7);
    int HuWv = Hu * Wv;
    int pxg[RB];
#pragma unroll
    for (int rb = 0; rb < RB; ++rb) {
        int n = n0 + rowS + rb * 32;
        int b = n / HuWv, r = n % HuWv;
        int u = r / Wv, v = r % Wv;
        pxg[rb] = ((b * Hpin + u) * Wpin + v) * Cin + dS * 8;
    }
    int aoff = (m0 + rowS) * Cin + dS * 8;

    char* AB = (char*)Alds;
    char* BB = (char*)Blds;

    int wm = (WAVES_M == 2) ? (wid & 1) : 0;
    int wn = (WAVES_M == 2) ? (wid >> 1) : wid;
    int cb = lane >> 4;
    int rm[FM], rn[FN];
#pragma unroll
    for (int mf = 0; mf < FM; ++mf) rm[mf] = wm * WM + mf * 16 + (lane & 15);
#pragma unroll
    for (int nf = 0; nf < FN; ++nf) rn[nf] = wn * WN + nf * 16 + (lane & 15);

    f32x4 acc[FM][FN];
#pragma unroll
    for (int mf = 0; mf < FM; ++mf)
#pragma unroll
        for (int nf = 0; nf < FN; ++nf) acc[mf][nf] = (f32x4){0.f, 0.f, 0.f, 0.f};

    for (int a = 0; a < ny; ++a) {
        int dy = (dys >> (4 * a)) & 15;
        for (int bx = 0; bx < nx; ++bx) {
            int dx = (dxs >> (4 * bx)) & 15;
            int tapoff = (dy * Wpin + dx) * Cin;
            const short* wblk = wt + (size_t)(a * nx + bx) * Mp * Cin;
            for (int cc = 0; cc < Cin; cc += 64) {
                __syncthreads();
                if (BM >= 32) {
#pragma unroll
                    for (int r = 0; r < BM / 32; ++r)
                        gll16(wblk + cc + aoff + r * 32 * Cin,
                              AB + r * 4096 + (wid << 10));
                } else {
                    if (wid < BM / 8) gll16(wblk + cc + aoff, AB + (wid << 10));
                }
#pragma unroll
                for (int rb = 0; rb < RB; ++rb)
                    gll16(pin + tapoff + cc + pxg[rb], BB + rb * 4096 + (wid << 10));
                __syncthreads();
#pragma unroll
                for (int h = 0; h < 2; ++h) {
                    bf16x8 av[FM], bv[FN];
#pragma unroll
                    for (int mf = 0; mf < FM; ++mf)
                        av[mf] = *(const bf16x8*)(AB + rm[mf] * 128 +
                                                  (((h * 4 + cb) ^ (rm[mf] & 7)) << 4));
#pragma unroll
                    for (int nf = 0; nf < FN; ++nf)
                        bv[nf] = *(const bf16x8*)(BB + rn[nf] * 128 +
                                                  (((h * 4 + cb) ^ (rn[nf] & 7)) << 4));
#pragma unroll
                    for (int mf = 0; mf < FM; ++mf)
#pragma unroll
                        for (int nf = 0; nf < FN; ++nf)
                            acc[mf][nf] = __builtin_amdgcn_mfma_f32_16x16x32_bf16(
                                av[mf], bv[nf], acc[mf][nf], 0, 0, 0);
                }
            }
        }
    }

#pragma unroll
    for (int mf = 0; mf < FM; ++mf) {
#pragma unroll
        for (int nf = 0; nf < FN; ++nf) {
            int p = n0 + wn * WN + nf * 16 + (lane & 15);
            int b = p / HuWv, r = p % HuWv;
            int u = r / Wv, v = r % Wv;
            int y = sy * u + py, x = sy * v + px;
            int cobase = m0 + wm * WM + mf * 16 + (lane >> 4) * 4;
            f32x4 vv = acc[mf][nf];
            if (OUTM == 1) {
                s16x4 pk;
#pragma unroll
                for (int reg = 0; reg < 4; ++reg) {
                    float f = vv[reg];
                    f = f > 0.f ? f : 0.f;
                    pk[reg] = f2bf(f);
                }
                *(s16x4*)(outb + (((size_t)b * Hop + y + poff) * Wop + (x + poff)) * Cout +
                          cobase) = pk;
            } else {
#pragma unroll
                for (int reg = 0; reg < 4; ++reg) {
                    int co = cobase + reg;
                    if (co < Cout) {
                        float f = vv[reg];
                        if (ACT == 0) f = f > 0.f ? f : 0.f;
                        else f = tanhf(f);
                        outb[((size_t)(b * Cout + co) * Ho + y) * Wo + x] = f2bf(f);
                    }
                }
            }
        }
    }
}

// ---------------------------------------------------------------------------

extern "C" void kernel_launch(void* const* d_in, const int* in_sizes, int n_in,
                              void* d_out, int out_size, void* d_ws, size_t ws_size,
                              hipStream_t stream) {
    const float* cont = (const float*)d_in[0];
    const float* w1 = (const float*)d_in[1];
    const float* w2 = (const float*)d_in[2];
    const float* w3 = (const float*)d_in[3];
    const float* w4 = (const float*)d_in[4];
    const float* w5 = (const float*)d_in[5];
    const float* w6 = (const float*)d_in[6];
    const float* kv0 = (const float*)d_in[7];
    const float* kh0 = (const float*)d_in[8];
    const float* m0 = (const float*)d_in[9];
    const float* kv1 = (const float*)d_in[10];
    const float* kh1 = (const float*)d_in[11];
    const float* m1 = (const float*)d_in[12];
    const float* kv2 = (const float*)d_in[13];
    const float* kh2 = (const float*)d_in[14];
    const float* m2 = (const float*)d_in[15];
    const float* kv3 = (const float*)d_in[16];
    const float* kh3 = (const float*)d_in[17];
    const float* m3 = (const float*)d_in[18];

    float* out = (float*)d_out;
    float* OUT0 = out;
    float* F8 = out + 1572864;
    float* F16 = out + 2097152;
    float* F32 = out + 18874368;

    const size_t MiB = 1 << 20;
    char* wsb = (char*)d_ws;
    short* WT = (short*)wsb;                  // [0,4)
    short* pin1 = (short*)(wsb + 4 * MiB);    // [4,5.2)
    short* t16b = (short*)(wsb + 6 * MiB);    // [6,39.6)
    short* pin2 = (short*)(wsb + 40 * MiB);   // [40,78)
    short* pin3 = (short*)(wsb + 80 * MiB);   // [80,97.8)
    short* t32bb = (short*)(wsb + 6 * MiB);   // [6,39.6)  (t16b dead)
    short* pin4 = (short*)(wsb + 40 * MiB);   // [40,75.7) (pin2 dead)
    short* pin5 = (short*)(wsb + 80 * MiB);   // [80,114.6)(pin3 dead)
    short* pin6 = (short*)(wsb + 6 * MiB);    // [6,75.2)  (t32bb,pin4 dead)
    short* toutb = (short*)(wsb + 76 * MiB);  // [76,79.2)

    short* wt1 = WT;                    // 9*512*64
    short* wt2 = wt1 + 294912;          // 9*256*512
    short* wt3 = wt2 + 1179648;         // 9*128*256
    short* wt4 = wt3 + 294912;          // 9*128*128
    short* wt5 = wt4 + 147456;          // 9*64*128
    short* wt6 = wt5 + 73728;           // 9*16*64

    auto wtr = [&](const float* w, short* wt, int Cin, int Cout, int Mp, int stride) {
        int total = 9 * Mp * Cin;
        wtrans_kernel<<<CDIV(total, 256), 256, 0, stream>>>(w, wt, Cin, Cout, Mp,
                                                            stride, total);
    };
    wtr(w1, wt1, 64, 512, 512, 2);
    wtr(w2, wt2, 512, 256, 256, 1);
    wtr(w3, wt3, 256, 128, 128, 2);
    wtr(w4, wt4, 128, 128, 128, 1);
    wtr(w5, wt5, 128, 64, 64, 2);
    wtr(w6, wt6, 64, 3, 16, 1);

    auto zb = [&](short* buf, int Hp, int Wp, int C8, int mode) {
        int zt = 32 * Hp * Wp * C8;
        zb_kernel<<<CDIV(zt, 256), 256, 0, stream>>>(buf, Hp, Wp, C8, mode, zt);
    };
    auto pad = [&](const float* src, short* pin, int C, int H, int W, int Hp, int Wp,
                   int po) {
        int total = 32 * Hp * Wp * (C >> 3);
        pad_kernel<<<CDIV(total, 256), 256, 0, stream>>>(src, pin, C, H, W, Hp, Wp, po,
                                                         total);
    };
    auto fusF = [&](const float* feat, const float* kv, const float* kh, const float* m,
                    float* o, int C, int H, int W) {
        int total = 32 * H * (C >> 2) * (W >> 2);
        fusionC_kernel<0><<<CDIV(total, 256), 256, 0, stream>>>(feat, kv, kh, m, o, 32,
                                                                C, H, W, total);
    };
    auto fusB = [&](const short* feat, const float* kv, const float* kh, const float* m,
                    float* o, int C, int H, int W) {
        int total = 32 * H * (C >> 2) * (W >> 2);
        fusionC_kernel<1><<<CDIV(total, 256), 256, 0, stream>>>(feat, kv, kh, m, o, 32,
                                                                C, H, W, total);
    };

    // 1. f8 = fusion(cont) -> F8 ; pad1: F8 -> pin1 (17x17x64, po=0)
    fusF(cont, kv0, kh0, m0, F8, 64, 16, 16);
    pad(F8, pin1, 64, 16, 16, 17, 17, 0);

    // 2. conv1 (s2): pin1 -> t16b bf16 NCHW [32,512,32,32]
    {
        dim3 g(32 * 16 * 16 / 128, 512 / 128, 4);
        convt_mfma<128, 128, true, 2, 0><<<g, 256, 0, stream>>>(
            pin1, wt1, nullptr, t16b, 17, 17, 64, 512, 512, 32, 32, 16, 16, 0, 0, 0);
    }
    // 3. f16 = fusion(t16b) -> F16 ; pad2: F16 -> pin2 (34x34x512, po=1)
    fusB(t16b, kv1, kh1, m1, F16, 512, 32, 32);
    pad(F16, pin2, 512, 32, 32, 34, 34, 1);

    // 4. conv2 (s1): pin2 -> pin3 (33x33x256 NHWC)
    zb(pin3, 33, 33, 32, 0);
    {
        dim3 g(32 * 32 * 32 / 128, 256 / 128, 1);
        convt_mfma<128, 128, false, 1, 0><<<g, 256, 0, stream>>>(
            pin2, wt2, nullptr, pin3, 34, 34, 512, 256, 256, 32, 32, 32, 32, 33, 33, 0);
    }
    // 5. conv3 (s2): pin3 -> t32bb bf16 NCHW [32,128,64,64]
    {
        dim3 g(32 * 32 * 32 / 128, 1, 4);
        convt_mfma<128, 128, true, 2, 0><<<g, 256, 0, stream>>>(
            pin3, wt3, nullptr, t32bb, 33, 33, 256, 128, 128, 64, 64, 32, 32, 0, 0, 0);
    }
    // 6. f32 = fusion(t32bb) -> F32 ; pad4: F32 -> pin4 (66x66x128, po=1)
    fusB(t32bb, kv2, kh2, m2, F32, 128, 64, 64);
    pad(F32, pin4, 128, 64, 64, 66, 66, 1);

    // 7. conv4 (s1): pin4 -> pin5 (65x65x128 NHWC)
    zb(pin5, 65, 65, 16, 0);
    {
        dim3 g(32 * 64 * 64 / 128, 1, 1);
        convt_mfma<128, 128, false, 1, 0><<<g, 256, 0, stream>>>(
            pin4, wt4, nullptr, pin5, 66, 66, 128, 128, 128, 64, 64, 64, 64, 65, 65, 0);
    }
    // 8. conv5 (s2): pin5 -> pin6 (130x130x64 NHWC, poff=1)
    zb(pin6, 130, 130, 8, 1);
    {
        dim3 g(32 * 64 * 64 / 128, 1, 4);
        convt_mfma<64, 128, true, 1, 0><<<g, 256, 0, stream>>>(
            pin5, wt5, nullptr, pin6, 65, 65, 128, 64, 64, 128, 128, 64, 64, 130, 130, 1);
    }
    // 9. conv6 (s1): pin6 -> toutb bf16 NCHW [32,3,128,128] tanh
    {
        dim3 g(32 * 128 * 128 / 64, 1, 1);
        convt_mfma<16, 64, false, 2, 1><<<g, 256, 0, stream>>>(
            pin6, wt6, nullptr, toutb, 130, 130, 64, 16, 3, 128, 128, 128, 128, 0, 0, 0);
    }
    // 10. out = fusion(toutb) -> OUT0 (C=3, bf16 input)
    {
        int total = 32 * 3 * 128 * (128 >> 2);
        fusion4b_kernel<<<CDIV(total, 256), 256, 0, stream>>>(toutb, kv3, kh3, m3, OUT0,
                                                              32, 3, 128, 128, total);
    }
}

// Round 6
// 598.352 us; speedup vs baseline: 1.1735x; 1.1735x over previous
//
#include <hip/hip_runtime.h>
#include <hip/hip_bf16.h>
#include <cmath>

#define CDIV(a, b) (((a) + (b) - 1) / (b))

typedef __attribute__((ext_vector_type(8))) short bf16x8;
typedef __attribute__((ext_vector_type(4))) short s16x4;
typedef __attribute__((ext_vector_type(4))) float f32x4;

__device__ __forceinline__ short f2bf(float f) {
    unsigned u = __float_as_uint(f);
    unsigned r = (u + 0x7fff + ((u >> 16) & 1)) >> 16;
    return (short)r;
}
__device__ __forceinline__ float bf2f(short s) {
    return __uint_as_float(((unsigned)(unsigned short)s) << 16);
}

__device__ __forceinline__ void gll16(const void* g, void* l) {
    __builtin_amdgcn_global_load_lds((const __attribute__((address_space(1))) void*)g,
                                     (__attribute__((address_space(3))) void*)l, 16, 0, 0);
}

// ---------------------------------------------------------------------------
// C-blocked fusion: 4 channels x 4 pixels per thread. TIN: 0 fp32, 1 bf16 NCHW.
// ---------------------------------------------------------------------------
template <int TIN>
__global__ void fusionC_kernel(const void* __restrict__ featv,
                               const float* __restrict__ kv,
                               const float* __restrict__ kh,
                               const float* __restrict__ m,
                               float* __restrict__ out,
                               int B, int C, int H, int W, int total) {
    int idx = blockIdx.x * blockDim.x + threadIdx.x;
    if (idx >= total) return;
    int Wg = W >> 2;
    int C4 = C >> 2;
    int g = idx % Wg;
    int cg = (idx / Wg) % C4;
    int y = (idx / (Wg * C4)) % H;
    int b = idx / (Wg * C4 * H);
    int x0 = g << 2, c0 = cg << 2;
    int HW = H * W;

    int yy[5];
#pragma unroll
    for (int i = 0; i < 5; ++i) {
        int t = y + i - 2;
        yy[i] = t < 0 ? 0 : (t >= H ? H - 1 : t);
    }
    const float* kvb = kv + ((size_t)b * 5 * H + y) * W + x0;
    const float* khb = kh + ((size_t)b * 5 * H + y) * W + x0;
    f32x4 kvv[5], khv[5];
#pragma unroll
    for (int i = 0; i < 5; ++i) {
        kvv[i] = *(const f32x4*)(kvb + (size_t)i * HW);
        khv[i] = *(const f32x4*)(khb + (size_t)i * HW);
    }
    f32x4 m4 = *(const f32x4*)(m + ((size_t)b * H + y) * W + x0);
    bool interior = (g >= 1 && g <= Wg - 2);

#pragma unroll
    for (int cc = 0; cc < 4; ++cc) {
        size_t plane = (size_t)(b * C + c0 + cc) * HW;
        const float* fpf = (const float*)featv + plane;
        const short* fpb = (const short*)featv + plane;
        f32x4 acc = (f32x4){0.f, 0.f, 0.f, 0.f};
        f32x4 ctr;
        if (interior) {
#pragma unroll
            for (int i = 0; i < 5; ++i) {
                float w8[8];
                if (TIN == 0) {
                    const float* row = fpf + (size_t)yy[i] * W + x0;
                    f32x4 Lv = *(const f32x4*)(row - 4);
                    f32x4 Cv = *(const f32x4*)(row);
                    f32x4 Rv = *(const f32x4*)(row + 4);
                    w8[0] = Lv[2]; w8[1] = Lv[3];
                    w8[2] = Cv[0]; w8[3] = Cv[1]; w8[4] = Cv[2]; w8[5] = Cv[3];
                    w8[6] = Rv[0]; w8[7] = Rv[1];
                    if (i == 2) ctr = Cv;
                } else {
                    const short* row = fpb + (size_t)yy[i] * W + x0;
                    s16x4 Lv = *(const s16x4*)(row - 4);
                    s16x4 Cv = *(const s16x4*)(row);
                    s16x4 Rv = *(const s16x4*)(row + 4);
                    w8[0] = bf2f(Lv[2]); w8[1] = bf2f(Lv[3]);
                    w8[2] = bf2f(Cv[0]); w8[3] = bf2f(Cv[1]);
                    w8[4] = bf2f(Cv[2]); w8[5] = bf2f(Cv[3]);
                    w8[6] = bf2f(Rv[0]); w8[7] = bf2f(Rv[1]);
                    if (i == 2) {
                        ctr[0] = w8[2]; ctr[1] = w8[3]; ctr[2] = w8[4]; ctr[3] = w8[5];
                    }
                }
#pragma unroll
                for (int o = 0; o < 4; ++o) {
                    float r = 0.f;
#pragma unroll
                    for (int j = 0; j < 5; ++j) r = fmaf(khv[j][o], w8[o + j], r);
                    acc[o] = fmaf(kvv[i][o], r, acc[o]);
                }
            }
        } else {
#pragma unroll
            for (int o = 0; o < 4; ++o) {
                int x = x0 + o;
                int xx[5];
#pragma unroll
                for (int j = 0; j < 5; ++j) {
                    int u = x + j - 2;
                    xx[j] = u < 0 ? 0 : (u >= W ? W - 1 : u);
                }
                float a = 0.f;
#pragma unroll
                for (int i = 0; i < 5; ++i) {
                    float r = 0.f;
#pragma unroll
                    for (int j = 0; j < 5; ++j) {
                        float fv = (TIN == 0) ? fpf[(size_t)yy[i] * W + xx[j]]
                                              : bf2f(fpb[(size_t)yy[i] * W + xx[j]]);
                        r = fmaf(khv[j][o], fv, r);
                    }
                    a = fmaf(kvv[i][o], r, a);
                }
                acc[o] = a;
                ctr[o] = (TIN == 0) ? fpf[(size_t)y * W + x] : bf2f(fpb[(size_t)y * W + x]);
            }
        }
        f32x4 o4;
#pragma unroll
        for (int o = 0; o < 4; ++o) o4[o] = m4[o] * acc[o] + (1.f - m4[o]) * ctr[o];
        *(f32x4*)(out + plane + (size_t)y * W + x0) = o4;
    }
}

// scalar-C fusion for C=3 final output, bf16 input
__global__ void fusion4b_kernel(const short* __restrict__ feat,
                                const float* __restrict__ kv,
                                const float* __restrict__ kh,
                                const float* __restrict__ m,
                                float* __restrict__ out,
                                int B, int C, int H, int W, int total) {
    int idx = blockIdx.x * blockDim.x + threadIdx.x;
    if (idx >= total) return;
    int Wg = W >> 2;
    int g = idx % Wg;
    int y = (idx / Wg) % H;
    int c = (idx / (Wg * H)) % C;
    int b = idx / (Wg * H * C);
    int x0 = g << 2;
    int HW = H * W;

    const short* fp = feat + (size_t)(b * C + c) * HW;
    int yy[5];
#pragma unroll
    for (int i = 0; i < 5; ++i) {
        int t = y + i - 2;
        yy[i] = t < 0 ? 0 : (t >= H ? H - 1 : t);
    }
    const float* kvb = kv + ((size_t)b * 5 * H + y) * W + x0;
    const float* khb = kh + ((size_t)b * 5 * H + y) * W + x0;

    f32x4 res, c4;
    if (g >= 1 && g <= Wg - 2) {
        f32x4 kvv[5], khv[5];
#pragma unroll
        for (int i = 0; i < 5; ++i) {
            kvv[i] = *(const f32x4*)(kvb + (size_t)i * HW);
            khv[i] = *(const f32x4*)(khb + (size_t)i * HW);
        }
        f32x4 acc = (f32x4){0.f, 0.f, 0.f, 0.f};
#pragma unroll
        for (int i = 0; i < 5; ++i) {
            const short* row = fp + (size_t)yy[i] * W + x0;
            s16x4 Lv = *(const s16x4*)(row - 4);
            s16x4 Cv = *(const s16x4*)(row);
            s16x4 Rv = *(const s16x4*)(row + 4);
            float w8[8] = {bf2f(Lv[2]), bf2f(Lv[3]), bf2f(Cv[0]), bf2f(Cv[1]),
                           bf2f(Cv[2]), bf2f(Cv[3]), bf2f(Rv[0]), bf2f(Rv[1])};
            if (i == 2) { c4[0] = w8[2]; c4[1] = w8[3]; c4[2] = w8[4]; c4[3] = w8[5]; }
#pragma unroll
            for (int o = 0; o < 4; ++o) {
                float r = 0.f;
#pragma unroll
                for (int j = 0; j < 5; ++j) r = fmaf(khv[j][o], w8[o + j], r);
                acc[o] = fmaf(kvv[i][o], r, acc[o]);
            }
        }
        res = acc;
    } else {
#pragma unroll
        for (int o = 0; o < 4; ++o) {
            int x = x0 + o;
            int xx[5];
#pragma unroll
            for (int j = 0; j < 5; ++j) {
                int u = x + j - 2;
                xx[j] = u < 0 ? 0 : (u >= W ? W - 1 : u);
            }
            float acc = 0.f;
#pragma unroll
            for (int i = 0; i < 5; ++i) {
                float r = 0.f;
#pragma unroll
                for (int j = 0; j < 5; ++j)
                    r = fmaf(khb[(size_t)j * HW + o], bf2f(fp[(size_t)yy[i] * W + xx[j]]), r);
                acc = fmaf(kvb[(size_t)i * HW + o], r, acc);
            }
            res[o] = acc;
            c4[o] = bf2f(fp[(size_t)y * W + x]);
        }
    }
    f32x4 m4 = *(const f32x4*)(m + ((size_t)b * H + y) * W + x0);
    f32x4 o4;
#pragma unroll
    for (int o = 0; o < 4; ++o) o4[o] = m4[o] * res[o] + (1.f - m4[o]) * c4[o];
    *(f32x4*)(out + ((size_t)(b * C + c) * H + y) * W + x0) = o4;
}

// ---------------------------------------------------------------------------
// Pad v2: fp32 NCHW -> bf16 NHWC, line-complete on BOTH sides.
// lane map: xp fastest (xt), then c8 (ct=256/xt). grid(nxt*cgroups, Hp, B).
// 16 lanes same-c8 read 16 consecutive x (full lines); lanes {l,l+xt,...}
// write contiguous NHWC chunks (full lines).
// ---------------------------------------------------------------------------
__global__ void pad_kernel(const float* __restrict__ in, short* __restrict__ pin,
                           int C, int H, int W, int Hp, int Wp, int po,
                           int xt, int nxt) {
    int b = blockIdx.z, yp = blockIdx.y;
    int ct = 256 / xt;
    int xtile = blockIdx.x % nxt;
    int cb = blockIdx.x / nxt;
    int xl = threadIdx.x % xt;
    int cl = threadIdx.x / xt;
    int xp = xtile * xt + xl;
    int c8 = cb * ct + cl;
    if (xp >= Wp) return;

    int y = yp - po, x = xp - po;
    bf16x8 v;
    if (y >= 0 && y < H && x >= 0 && x < W) {
        const float* ip = in + ((size_t)(b * C + c8 * 8) * H + y) * W + x;
        size_t HW = (size_t)H * W;
#pragma unroll
        for (int k = 0; k < 8; ++k) v[k] = f2bf(ip[k * HW]);
    } else {
        v = (bf16x8)0;
    }
    *(bf16x8*)(pin + (((size_t)b * Hp + yp) * Wp + xp) * C + c8 * 8) = v;
}

// zero pad borders of NHWC bf16 pin. mode1: all 4 edges; mode0: high edges only.
__global__ void zb_kernel(short* __restrict__ buf, int Hp, int Wp, int C8, int mode,
                          int total) {
    int tid = blockIdx.x * blockDim.x + threadIdx.x;
    if (tid >= total) return;
    int xp = (tid / C8) % Wp;
    int yp = (tid / (C8 * Wp)) % Hp;
    bool border = mode ? (yp == 0 || yp == Hp - 1 || xp == 0 || xp == Wp - 1)
                       : (yp == Hp - 1 || xp == Wp - 1);
    if (border) *(bf16x8*)(buf + (size_t)tid * 8) = (bf16x8)0;
}

// ---------------------------------------------------------------------------
// Weight transform (verified): wt[t9][m][ci]; s2 packs phase blocks
// {1,2,2,4} at offsets {0,1,3,5}.
// ---------------------------------------------------------------------------
__global__ void wtrans_kernel(const float* __restrict__ w, short* __restrict__ wt,
                              int Cin, int Cout, int Mp, int stride, int total) {
    int tid = blockIdx.x * blockDim.x + threadIdx.x;
    if (tid >= total) return;
    int ci = tid % Cin;
    int mm = (tid / Cin) % Mp;
    int t9 = tid / (Cin * Mp);
    int i, j;
    if (stride == 1) {
        int a = t9 / 3, bb = t9 % 3;
        i = 2 - a; j = 2 - bb;
    } else {
        int py, px, a, bb;
        if (t9 == 0) { py = 0; px = 0; a = 0; bb = 0; }
        else if (t9 < 3) { py = 0; px = 1; a = 0; bb = t9 - 1; }
        else if (t9 < 5) { py = 1; px = 0; a = t9 - 3; bb = 0; }
        else { int tt = t9 - 5; py = 1; px = 1; a = tt >> 1; bb = tt & 1; }
        i = (py == 0) ? 1 : (a == 0 ? 2 : 0);
        j = (px == 0) ? 1 : (bb == 0 ? 2 : 0);
    }
    float v = 0.f;
    if (mm < Cout) v = w[((ci * Cout + mm) * 3 + i) * 3 + j];
    wt[tid] = f2bf(v);
}

// ---------------------------------------------------------------------------
// Implicit-GEMM convT, BM x BN tile, 4 waves, BK=64, XOR-swizzled LDS.
// K-loop: cc OUTER, taps inner (L2 reuse of neighboring pixels per cc-slice).
// S2: blockIdx.z = phase. OUTM 1: bf16 NHWC pin. OUTM 2: bf16 NCHW (+act).
// ---------------------------------------------------------------------------
template <int BM, int BN, bool S2, int OUTM, int ACT>
__global__ void convt_mfma(const short* __restrict__ pin, const short* __restrict__ wtc,
                           float* __restrict__ outf, short* __restrict__ outb,
                           int Hpin, int Wpin, int Cin, int Mp, int Cout,
                           int Ho, int Wo, int Hu, int Wv,
                           int Hop, int Wop, int poff) {
    constexpr int WAVES_M = (BM >= 128) ? 2 : 1;
    constexpr int WM = BM / WAVES_M;
    constexpr int WN = BN / (4 / WAVES_M);
    constexpr int FM = WM / 16, FN = WN / 16;
    constexpr int RB = BN / 32;
    __shared__ __align__(16) short Alds[BM * 64];
    __shared__ __align__(16) short Blds[BN * 64];

    int t = threadIdx.x, lane = t & 63, wid = t >> 6;
    int n0 = blockIdx.x * BN, m0 = blockIdx.y * BM;

    int py = 0, px = 0, ny = 3, nx = 3, dys = 0x210, dxs = 0x210, sy = 1;
    const short* wt = wtc;
    if (S2) {
        int pz = blockIdx.z;
        py = pz >> 1; px = pz & 1;
        ny = 1 + py; nx = 1 + px;
        dys = py ? 0x10 : 0; dxs = px ? 0x10 : 0;
        int pre = (pz == 0) ? 0 : (pz == 1) ? 1 : (pz == 2) ? 3 : 5;
        wt = wtc + (size_t)pre * Mp * Cin;
        sy = 2;
    }

    int rowS = t >> 3;
    int dS = (t & 7) ^ (rowS & 7);
    int HuWv = Hu * Wv;
    int pxg[RB];
#pragma unroll
    for (int rb = 0; rb < RB; ++rb) {
        int n = n0 + rowS + rb * 32;
        int b = n / HuWv, r = n % HuWv;
        int u = r / Wv, v = r % Wv;
        pxg[rb] = ((b * Hpin + u) * Wpin + v) * Cin + dS * 8;
    }
    int aoff = (m0 + rowS) * Cin + dS * 8;

    char* AB = (char*)Alds;
    char* BB = (char*)Blds;

    int wm = (WAVES_M == 2) ? (wid & 1) : 0;
    int wn = (WAVES_M == 2) ? (wid >> 1) : wid;
    int cb = lane >> 4;
    int rm[FM], rn[FN];
#pragma unroll
    for (int mf = 0; mf < FM; ++mf) rm[mf] = wm * WM + mf * 16 + (lane & 15);
#pragma unroll
    for (int nf = 0; nf < FN; ++nf) rn[nf] = wn * WN + nf * 16 + (lane & 15);

    f32x4 acc[FM][FN];
#pragma unroll
    for (int mf = 0; mf < FM; ++mf)
#pragma unroll
        for (int nf = 0; nf < FN; ++nf) acc[mf][nf] = (f32x4){0.f, 0.f, 0.f, 0.f};

    for (int cc = 0; cc < Cin; cc += 64) {
        for (int a = 0; a < ny; ++a) {
            int dy = (dys >> (4 * a)) & 15;
            for (int bx = 0; bx < nx; ++bx) {
                int dx = (dxs >> (4 * bx)) & 15;
                int tapoff = (dy * Wpin + dx) * Cin;
                const short* wblk = wt + (size_t)(a * nx + bx) * Mp * Cin;
                __syncthreads();
                if (BM >= 32) {
#pragma unroll
                    for (int r = 0; r < BM / 32; ++r)
                        gll16(wblk + cc + aoff + r * 32 * Cin,
                              AB + r * 4096 + (wid << 10));
                } else {
                    if (wid < BM / 8) gll16(wblk + cc + aoff, AB + (wid << 10));
                }
#pragma unroll
                for (int rb = 0; rb < RB; ++rb)
                    gll16(pin + tapoff + cc + pxg[rb], BB + rb * 4096 + (wid << 10));
                __syncthreads();
#pragma unroll
                for (int h = 0; h < 2; ++h) {
                    bf16x8 av[FM], bv[FN];
#pragma unroll
                    for (int mf = 0; mf < FM; ++mf)
                        av[mf] = *(const bf16x8*)(AB + rm[mf] * 128 +
                                                  (((h * 4 + cb) ^ (rm[mf] & 7)) << 4));
#pragma unroll
                    for (int nf = 0; nf < FN; ++nf)
                        bv[nf] = *(const bf16x8*)(BB + rn[nf] * 128 +
                                                  (((h * 4 + cb) ^ (rn[nf] & 7)) << 4));
#pragma unroll
                    for (int mf = 0; mf < FM; ++mf)
#pragma unroll
                        for (int nf = 0; nf < FN; ++nf)
                            acc[mf][nf] = __builtin_amdgcn_mfma_f32_16x16x32_bf16(
                                av[mf], bv[nf], acc[mf][nf], 0, 0, 0);
                }
            }
        }
    }

#pragma unroll
    for (int mf = 0; mf < FM; ++mf) {
#pragma unroll
        for (int nf = 0; nf < FN; ++nf) {
            int p = n0 + wn * WN + nf * 16 + (lane & 15);
            int b = p / HuWv, r = p % HuWv;
            int u = r / Wv, v = r % Wv;
            int y = sy * u + py, x = sy * v + px;
            int cobase = m0 + wm * WM + mf * 16 + (lane >> 4) * 4;
            f32x4 vv = acc[mf][nf];
            if (OUTM == 1) {
                s16x4 pk;
#pragma unroll
                for (int reg = 0; reg < 4; ++reg) {
                    float f = vv[reg];
                    f = f > 0.f ? f : 0.f;
                    pk[reg] = f2bf(f);
                }
                *(s16x4*)(outb + (((size_t)b * Hop + y + poff) * Wop + (x + poff)) * Cout +
                          cobase) = pk;
            } else {
#pragma unroll
                for (int reg = 0; reg < 4; ++reg) {
                    int co = cobase + reg;
                    if (co < Cout) {
                        float f = vv[reg];
                        if (ACT == 0) f = f > 0.f ? f : 0.f;
                        else f = tanhf(f);
                        outb[((size_t)(b * Cout + co) * Ho + y) * Wo + x] = f2bf(f);
                    }
                }
            }
        }
    }
}

// ---------------------------------------------------------------------------

extern "C" void kernel_launch(void* const* d_in, const int* in_sizes, int n_in,
                              void* d_out, int out_size, void* d_ws, size_t ws_size,
                              hipStream_t stream) {
    const float* cont = (const float*)d_in[0];
    const float* w1 = (const float*)d_in[1];
    const float* w2 = (const float*)d_in[2];
    const float* w3 = (const float*)d_in[3];
    const float* w4 = (const float*)d_in[4];
    const float* w5 = (const float*)d_in[5];
    const float* w6 = (const float*)d_in[6];
    const float* kv0 = (const float*)d_in[7];
    const float* kh0 = (const float*)d_in[8];
    const float* m0 = (const float*)d_in[9];
    const float* kv1 = (const float*)d_in[10];
    const float* kh1 = (const float*)d_in[11];
    const float* m1 = (const float*)d_in[12];
    const float* kv2 = (const float*)d_in[13];
    const float* kh2 = (const float*)d_in[14];
    const float* m2 = (const float*)d_in[15];
    const float* kv3 = (const float*)d_in[16];
    const float* kh3 = (const float*)d_in[17];
    const float* m3 = (const float*)d_in[18];

    float* out = (float*)d_out;
    float* OUT0 = out;
    float* F8 = out + 1572864;
    float* F16 = out + 2097152;
    float* F32 = out + 18874368;

    const size_t MiB = 1 << 20;
    char* wsb = (char*)d_ws;
    short* WT = (short*)wsb;                  // [0,4)
    short* pin1 = (short*)(wsb + 4 * MiB);    // [4,5.2)
    short* t16b = (short*)(wsb + 6 * MiB);    // [6,39.6)
    short* pin2 = (short*)(wsb + 40 * MiB);   // [40,78)
    short* pin3 = (short*)(wsb + 80 * MiB);   // [80,97.8)
    short* t32bb = (short*)(wsb + 6 * MiB);   // [6,39.6)  (t16b dead)
    short* pin4 = (short*)(wsb + 40 * MiB);   // [40,75.7) (pin2 dead)
    short* pin5 = (short*)(wsb + 80 * MiB);   // [80,114.6)(pin3 dead)
    short* pin6 = (short*)(wsb + 6 * MiB);    // [6,75.2)  (t32bb,pin4 dead)
    short* toutb = (short*)(wsb + 76 * MiB);  // [76,79.2)

    short* wt1 = WT;                    // 9*512*64
    short* wt2 = wt1 + 294912;          // 9*256*512
    short* wt3 = wt2 + 1179648;         // 9*128*256
    short* wt4 = wt3 + 294912;          // 9*128*128
    short* wt5 = wt4 + 147456;          // 9*64*128
    short* wt6 = wt5 + 73728;           // 9*16*64

    auto wtr = [&](const float* w, short* wt, int Cin, int Cout, int Mp, int stride) {
        int total = 9 * Mp * Cin;
        wtrans_kernel<<<CDIV(total, 256), 256, 0, stream>>>(w, wt, Cin, Cout, Mp,
                                                            stride, total);
    };
    wtr(w1, wt1, 64, 512, 512, 2);
    wtr(w2, wt2, 512, 256, 256, 1);
    wtr(w3, wt3, 256, 128, 128, 2);
    wtr(w4, wt4, 128, 128, 128, 1);
    wtr(w5, wt5, 128, 64, 64, 2);
    wtr(w6, wt6, 64, 3, 16, 1);

    auto zb = [&](short* buf, int Hp, int Wp, int C8, int mode) {
        int zt = 32 * Hp * Wp * C8;
        zb_kernel<<<CDIV(zt, 256), 256, 0, stream>>>(buf, Hp, Wp, C8, mode, zt);
    };
    auto pad = [&](const float* src, short* pin, int C, int H, int W, int Hp, int Wp,
                   int po) {
        int C8 = C >> 3;
        int xt = (C8 >= 16) ? 16 : 32;       // lanes per x-tile
        int ct = 256 / xt;                   // c8 groups per block
        int nxt = CDIV(Wp, xt);
        dim3 g(nxt * (C8 / ct < 1 ? 1 : C8 / ct), Hp, 32);
        // when C8 < ct, some lanes exceed C8 -> guard via grid: C8/ct>=1 for all our cases
        pad_kernel<<<g, 256, 0, stream>>>(src, pin, C, H, W, Hp, Wp, po, xt, nxt);
    };
    auto fusF = [&](const float* feat, const float* kv, const float* kh, const float* m,
                    float* o, int C, int H, int W) {
        int total = 32 * H * (C >> 2) * (W >> 2);
        fusionC_kernel<0><<<CDIV(total, 256), 256, 0, stream>>>(feat, kv, kh, m, o, 32,
                                                                C, H, W, total);
    };
    auto fusB = [&](const short* feat, const float* kv, const float* kh, const float* m,
                    float* o, int C, int H, int W) {
        int total = 32 * H * (C >> 2) * (W >> 2);
        fusionC_kernel<1><<<CDIV(total, 256), 256, 0, stream>>>(feat, kv, kh, m, o, 32,
                                                                C, H, W, total);
    };

    // 1. f8 = fusion(cont) -> F8 ; pad1: F8 -> pin1 (17x17x64, po=0)
    fusF(cont, kv0, kh0, m0, F8, 64, 16, 16);
    pad(F8, pin1, 64, 16, 16, 17, 17, 0);

    // 2. conv1 (s2): pin1 -> t16b bf16 NCHW [32,512,32,32]
    {
        dim3 g(32 * 16 * 16 / 128, 512 / 128, 4);
        convt_mfma<128, 128, true, 2, 0><<<g, 256, 0, stream>>>(
            pin1, wt1, nullptr, t16b, 17, 17, 64, 512, 512, 32, 32, 16, 16, 0, 0, 0);
    }
    // 3. f16 = fusion(t16b) -> F16 ; pad2: F16 -> pin2 (34x34x512, po=1)
    fusB(t16b, kv1, kh1, m1, F16, 512, 32, 32);
    pad(F16, pin2, 512, 32, 32, 34, 34, 1);

    // 4. conv2 (s1): pin2 -> pin3 (33x33x256 NHWC)
    zb(pin3, 33, 33, 32, 0);
    {
        dim3 g(32 * 32 * 32 / 128, 256 / 128, 1);
        convt_mfma<128, 128, false, 1, 0><<<g, 256, 0, stream>>>(
            pin2, wt2, nullptr, pin3, 34, 34, 512, 256, 256, 32, 32, 32, 32, 33, 33, 0);
    }
    // 5. conv3 (s2): pin3 -> t32bb bf16 NCHW [32,128,64,64]
    {
        dim3 g(32 * 32 * 32 / 128, 1, 4);
        convt_mfma<128, 128, true, 2, 0><<<g, 256, 0, stream>>>(
            pin3, wt3, nullptr, t32bb, 33, 33, 256, 128, 128, 64, 64, 32, 32, 0, 0, 0);
    }
    // 6. f32 = fusion(t32bb) -> F32 ; pad4: F32 -> pin4 (66x66x128, po=1)
    fusB(t32bb, kv2, kh2, m2, F32, 128, 64, 64);
    pad(F32, pin4, 128, 64, 64, 66, 66, 1);

    // 7. conv4 (s1): pin4 -> pin5 (65x65x128 NHWC)
    zb(pin5, 65, 65, 16, 0);
    {
        dim3 g(32 * 64 * 64 / 128, 1, 1);
        convt_mfma<128, 128, false, 1, 0><<<g, 256, 0, stream>>>(
            pin4, wt4, nullptr, pin5, 66, 66, 128, 128, 128, 64, 64, 64, 64, 65, 65, 0);
    }
    // 8. conv5 (s2): pin5 -> pin6 (130x130x64 NHWC, poff=1)
    zb(pin6, 130, 130, 8, 1);
    {
        dim3 g(32 * 64 * 64 / 128, 1, 4);
        convt_mfma<64, 128, true, 1, 0><<<g, 256, 0, stream>>>(
            pin5, wt5, nullptr, pin6, 65, 65, 128, 64, 64, 128, 128, 64, 64, 130, 130, 1);
    }
    // 9. conv6 (s1): pin6 -> toutb bf16 NCHW [32,3,128,128] tanh
    {
        dim3 g(32 * 128 * 128 / 64, 1, 1);
        convt_mfma<16, 64, false, 2, 1><<<g, 256, 0, stream>>>(
            pin6, wt6, nullptr, toutb, 130, 130, 64, 16, 3, 128, 128, 128, 128, 0, 0, 0);
    }
    // 10. out = fusion(toutb) -> OUT0 (C=3, bf16 input)
    {
        int total = 32 * 3 * 128 * (128 >> 2);
        fusion4b_kernel<<<CDIV(total, 256), 256, 0, stream>>>(toutb, kv3, kh3, m3, OUT0,
                                                              32, 3, 128, 128, total);
    }
}